// Round 8
// baseline (7706.468 us; speedup 1.0000x reference)
//
#include <hip/hip_runtime.h>

// Fully-fused weight-stationary stacked-LSTM, v8: ONE 1024-thread block per
// 16 batches (grid=64). All weights (1.01 MB fp16 MFMA A-fragments) live in
// the block's register file (16 waves: L3 tile each; waves 0-3 + L1 tiles;
// waves 4-11 + L2 tiles). All recurrences LDS-local. No inter-block sync at
// all. 2 barriers/step main phase, +2 in the 16 LIN steps.

#define NT 1024
#define T_SEQ 256

#define NJT1 4
#define NJT2 8
#define NJT3 16
#define NKB1 3     // K1 = 66 -> padded 96  [h1(64) | x(2) | pad]
#define NKB2 6     // K2 = 192              [h1(64) | h2(128)]
#define NKB3 12    // K3 = 384              [h2(128) | h3(256)]

#define WSZ1 (NJT1*4*NKB1*512)   // 24576 halfs
#define WSZ2 (NJT2*4*NKB2*512)   // 98304
#define WSZ3 (NJT3*4*NKB3*512)   // 393216
#define WTOT (WSZ1+WSZ2+WSZ3)    // 516096 halfs ~ 1.01 MB

// LDS strides (halfs): 136/200/392 = 68/100/196 dw, all == 4 mod 32 -> no conflicts
#define XS1 136
#define XS2 200
#define XS3 392

typedef _Float16 half8 __attribute__((ext_vector_type(8)));
typedef _Float16 half4 __attribute__((ext_vector_type(4)));
typedef float f32x4 __attribute__((ext_vector_type(4)));

__device__ __forceinline__ float sigm(float x) {
  return __fdividef(1.f, 1.f + __expf(-x));
}
__device__ __forceinline__ float tanh_fast(float x) {
  float t = __expf(-2.f * fabsf(x));
  float r = __fdividef(1.f - t, 1.f + t);
  return copysignf(r, x);
}

// ---- prep: fp32 weights -> f16 MFMA A-fragment layout (verified R2-R5) --------
// lane l holds 8 halfs: row = tilebase + (l&15), k = kk*32 + (l>>4)*8 + j.
__global__ void prep_weights(const float* __restrict__ Wih1, const float* __restrict__ Whh1,
                             const float* __restrict__ Wih2, const float* __restrict__ Whh2,
                             const float* __restrict__ Wih3, const float* __restrict__ Whh3,
                             _Float16* __restrict__ WT) {
  int idx = blockIdx.x * blockDim.x + threadIdx.x;
  if (idx >= WTOT) return;
  float v = 0.f;
  if (idx < WSZ1) {
    const int e = idx, blk = e >> 9, wb = e & 511;
    const int lane = wb >> 3, j = wb & 7;
    const int tl = blk / NKB1, kk = blk % NKB1;
    const int q = tl / NJT1, jt = tl % NJT1;
    const int r = q * 64 + jt * 16 + (lane & 15);
    const int k = kk * 32 + ((lane >> 4) << 3) + j;
    if (k < 64)       v = Whh1[r * 64 + k];          // h1 at k 0..63
    else if (k < 66)  v = Wih1[r * 2 + (k - 64)];    // x at k 64,65
  } else if (idx < WSZ1 + WSZ2) {
    const int e = idx - WSZ1, blk = e >> 9, wb = e & 511;
    const int lane = wb >> 3, j = wb & 7;
    const int tl = blk / NKB2, kk = blk % NKB2;
    const int q = tl / NJT2, jt = tl % NJT2;
    const int r = q * 128 + jt * 16 + (lane & 15);
    const int k = kk * 32 + ((lane >> 4) << 3) + j;
    if (k < 64)       v = Wih2[r * 64 + k];          // h1
    else              v = Whh2[r * 128 + (k - 64)];  // h2
  } else {
    const int e = idx - WSZ1 - WSZ2, blk = e >> 9, wb = e & 511;
    const int lane = wb >> 3, j = wb & 7;
    const int tl = blk / NKB3, kk = blk % NKB3;
    const int q = tl / NJT3, jt = tl % NJT3;
    const int r = q * 256 + jt * 16 + (lane & 15);
    const int k = kk * 32 + ((lane >> 4) << 3) + j;
    if (k < 128)      v = Wih3[r * 128 + k];          // h2
    else              v = Whh3[r * 256 + (k - 128)];  // h3
  }
  WT[idx] = (_Float16)v;
}

// ---- main fused kernel --------------------------------------------------------
__global__ __launch_bounds__(NT, 1) void lstm_fused(
    const float* __restrict__ input, const int* __restrict__ future_p,
    const float* __restrict__ bih1, const float* __restrict__ bhh1,
    const float* __restrict__ bih2, const float* __restrict__ bhh2,
    const float* __restrict__ bih3, const float* __restrict__ bhh3,
    const float* __restrict__ Wlin, const float* __restrict__ blin,
    const _Float16* __restrict__ WT,
    float* __restrict__ out) {
  __shared__ __align__(16) _Float16 xh1[16][XS1];  // [h1(64)|x(2)|pad96]
  __shared__ __align__(16) _Float16 xh2[16][XS2];  // [h1(64)|h2(128)|pad]
  __shared__ __align__(16) _Float16 xh3[16][XS3];  // [h2(128)|h3(256)|pad]
  __shared__ float wlin[2][448];
  __shared__ float bs1[256], bs2[512], bs3[1024];

  const int tid = threadIdx.x;
  const int w = tid >> 6, lane = tid & 63;
  const int n = lane & 15, l4 = lane >> 4;
  const int b0 = blockIdx.x * 16;

  // ---- init LDS (pads stay zero; zero h-state = correct t=0) ----
  for (int i = tid; i < 16 * XS1; i += NT) (&xh1[0][0])[i] = (_Float16)0.f;
  for (int i = tid; i < 16 * XS2; i += NT) (&xh2[0][0])[i] = (_Float16)0.f;
  for (int i = tid; i < 16 * XS3; i += NT) (&xh3[0][0])[i] = (_Float16)0.f;
  if (tid < 896) (&wlin[0][0])[tid] = Wlin[tid];
  if (tid < 256) bs1[tid] = bih1[tid] + bhh1[tid];
  if (tid < 512) bs2[tid] = bih2[tid] + bhh2[tid];
  bs3[tid] = bih3[tid] + bhh3[tid];
  if (tid < 32) {  // x(0)
    const int nn = tid >> 1, ch = tid & 1;
    xh1[nn][64 + ch] = (_Float16)input[((size_t)(b0 + nn) * T_SEQ + 0) * 2 + ch];
  }

  // ---- weights into registers ----
  half8 a3[4][12];
#pragma unroll
  for (int q = 0; q < 4; ++q)
#pragma unroll
    for (int kk = 0; kk < 12; ++kk)
      a3[q][kk] = *(const half8*)(WT + WSZ1 + WSZ2 + ((q*NJT3 + w)*NKB3 + kk)*512 + lane*8);
  half8 a1[4][3];
  half8 a2[4][6];
  if (w < 4) {
#pragma unroll
    for (int q = 0; q < 4; ++q)
#pragma unroll
      for (int kk = 0; kk < 3; ++kk)
        a1[q][kk] = *(const half8*)(WT + ((q*NJT1 + w)*NKB1 + kk)*512 + lane*8);
  } else if (w < 12) {
    const int tile = w - 4;
#pragma unroll
    for (int q = 0; q < 4; ++q)
#pragma unroll
      for (int kk = 0; kk < 6; ++kk)
        a2[q][kk] = *(const half8*)(WT + WSZ1 + ((q*NJT2 + tile)*NKB2 + kk)*512 + lane*8);
  }
  float c1[4] = {}, c2[4] = {}, c3[4] = {};

  const int fut = *future_p;             // 16
  const int nsteps = T_SEQ - 1 + fut;    // 271
  __syncthreads();

  for (int t = 0; t < nsteps; ++t) {
    // ---- A: L1 (waves 0-3, tile w) ----
    if (w < 4) {
      half8 bf[3];
#pragma unroll
      for (int kk = 0; kk < 3; ++kk)
        bf[kk] = *(const half8*)(&xh1[n][kk*32 + l4*8]);
      f32x4 acc[4];
#pragma unroll
      for (int q = 0; q < 4; ++q)
        acc[q] = *(const f32x4*)(&bs1[q*64 + w*16 + l4*4]);
#pragma unroll
      for (int q = 0; q < 4; ++q)
#pragma unroll
        for (int kk = 0; kk < 3; ++kk)
          acc[q] = __builtin_amdgcn_mfma_f32_16x16x32_f16(a1[q][kk], bf[kk], acc[q], 0, 0, 0);
      half4 hv;
#pragma unroll
      for (int e = 0; e < 4; ++e) {
        const float cn = sigm(acc[1][e]) * c1[e] + sigm(acc[0][e]) * tanh_fast(acc[2][e]);
        const float h = sigm(acc[3][e]) * tanh_fast(cn);
        c1[e] = cn;
        hv[e] = (_Float16)h;
      }
      *(half4*)(&xh1[n][w*16 + l4*4]) = hv;
      *(half4*)(&xh2[n][w*16 + l4*4]) = hv;
    }
    __syncthreads();  // bar1: h1 ready

    // ---- B: L2 (waves 4-11, tile w-4); x-feed (wave 12) ----
    if (w >= 4 && w < 12) {
      const int tile = w - 4;
      half8 bf[6];
#pragma unroll
      for (int kk = 0; kk < 6; ++kk)
        bf[kk] = *(const half8*)(&xh2[n][kk*32 + l4*8]);
      f32x4 acc[4];
#pragma unroll
      for (int q = 0; q < 4; ++q)
        acc[q] = *(const f32x4*)(&bs2[q*128 + tile*16 + l4*4]);
#pragma unroll
      for (int q = 0; q < 4; ++q)
#pragma unroll
        for (int kk = 0; kk < 6; ++kk)
          acc[q] = __builtin_amdgcn_mfma_f32_16x16x32_f16(a2[q][kk], bf[kk], acc[q], 0, 0, 0);
      half4 hv;
#pragma unroll
      for (int e = 0; e < 4; ++e) {
        const float cn = sigm(acc[1][e]) * c2[e] + sigm(acc[0][e]) * tanh_fast(acc[2][e]);
        const float h = sigm(acc[3][e]) * tanh_fast(cn);
        c2[e] = cn;
        hv[e] = (_Float16)h;
      }
      *(half4*)(&xh2[n][64 + tile*16 + l4*4]) = hv;
      *(half4*)(&xh3[n][tile*16 + l4*4]) = hv;
    } else if (w == 12 && t + 1 < T_SEQ && lane < 32) {
      const int nn = lane >> 1, ch = lane & 1;
      xh1[nn][64 + ch] =
          (_Float16)input[((size_t)(b0 + nn) * T_SEQ + (t + 1)) * 2 + ch];
    }
    __syncthreads();  // bar2: h2 ready (+ next x)

    // ---- C: L3 (all 16 waves, tile w) ----
    {
      half8 bf[12];
#pragma unroll
      for (int kk = 0; kk < 12; ++kk)
        bf[kk] = *(const half8*)(&xh3[n][kk*32 + l4*8]);
      f32x4 acc[4];
#pragma unroll
      for (int q = 0; q < 4; ++q)
        acc[q] = *(const f32x4*)(&bs3[q*256 + w*16 + l4*4]);
#pragma unroll
      for (int q = 0; q < 4; ++q)
#pragma unroll
        for (int kk = 0; kk < 12; ++kk)
          acc[q] = __builtin_amdgcn_mfma_f32_16x16x32_f16(a3[q][kk], bf[kk], acc[q], 0, 0, 0);
      half4 hv;
#pragma unroll
      for (int e = 0; e < 4; ++e) {
        const float cn = sigm(acc[1][e]) * c3[e] + sigm(acc[0][e]) * tanh_fast(acc[2][e]);
        const float h = sigm(acc[3][e]) * tanh_fast(cn);
        c3[e] = cn;
        hv[e] = (_Float16)h;
      }
      *(half4*)(&xh3[n][128 + w*16 + l4*4]) = hv;
    }

    // ---- LIN (t >= 255): out(t) and x(t+1) ----
    if (t >= T_SEQ - 1) {
      __syncthreads();  // bar3: h3 ready
      if (w < 8) {
        const int grp = lane >> 4, l16 = lane & 15;
        const int job = w * 4 + grp;        // 0..31
        const int nn = job >> 1, ch = job & 1;
        float acc = 0.f;
#pragma unroll
        for (int i = 0; i < 7; ++i) {
          const int k = l16 * 4 + i * 64;
          const half4 xv = (k < 192) ? *(const half4*)(&xh2[nn][k])
                                     : *(const half4*)(&xh3[nn][128 + (k - 192)]);
          const float* wl = &wlin[ch][k];
          acc = fmaf(wl[0], (float)xv[0], acc);
          acc = fmaf(wl[1], (float)xv[1], acc);
          acc = fmaf(wl[2], (float)xv[2], acc);
          acc = fmaf(wl[3], (float)xv[3], acc);
        }
        acc += __shfl_xor(acc, 1, 16);
        acc += __shfl_xor(acc, 2, 16);
        acc += __shfl_xor(acc, 4, 16);
        acc += __shfl_xor(acc, 8, 16);
        if (l16 == 0) {
          const float o = acc + blin[ch];
          out[((size_t)(b0 + nn) * fut + (t - (T_SEQ - 1))) * 2 + ch] = o;
          xh1[nn][64 + ch] = (_Float16)o;   // x for step t+1
        }
      }
      __syncthreads();  // bar4: x ready for next A
    }
  }
}

extern "C" void kernel_launch(void* const* d_in, const int* in_sizes, int n_in,
                              void* d_out, int out_size, void* d_ws, size_t ws_size,
                              hipStream_t stream) {
  const float* input = (const float*)d_in[0];
  const int*   fut   = (const int*)d_in[1];
  const float* Wih1  = (const float*)d_in[2];
  const float* Whh1  = (const float*)d_in[3];
  const float* bih1  = (const float*)d_in[4];
  const float* bhh1  = (const float*)d_in[5];
  const float* Wih2  = (const float*)d_in[6];
  const float* Whh2  = (const float*)d_in[7];
  const float* bih2  = (const float*)d_in[8];
  const float* bhh2  = (const float*)d_in[9];
  const float* Wih3  = (const float*)d_in[10];
  const float* Whh3  = (const float*)d_in[11];
  const float* bih3  = (const float*)d_in[12];
  const float* bhh3  = (const float*)d_in[13];
  const float* Wlin  = (const float*)d_in[14];
  const float* blin  = (const float*)d_in[15];
  float* out = (float*)d_out;

  _Float16* WT = (_Float16*)d_ws;  // 516096 halfs ~ 1.01 MB

  prep_weights<<<(WTOT + 255) / 256, 256, 0, stream>>>(Wih1, Whh1, Wih2, Whh2, Wih3, Whh3, WT);
  lstm_fused<<<64, NT, 0, stream>>>(input, fut,
                                    bih1, bhh1, bih2, bhh2, bih3, bhh3,
                                    Wlin, blin, WT, out);
}

// Round 9
// 3656.008 us; speedup vs baseline: 2.1079x; 2.1079x over previous
//
#include <hip/hip_runtime.h>

// Weight-stationary pipelined stacked-LSTM, v9.
// 32 teams x 3 blocks (96 blocks, 256 thr): role 0 = front (L1+L2+LIN combine),
// roles 1,2 = L3 halves (8 tiles each, 2 tiles/wave = 384 weight VGPRs).
// Cross-block comm: R5-proven system-scope relaxed atomics (+vmcnt fence).
// h3 recurrence: own half local (LDS), sibling half = 1 remote hop/step.
// Halves compute LIN partials for their h3 range -> future phase is 2 hops.
// Watchdog-capped spins (no timeout possible).

#define T_SEQ 256
#define NTEAM 32
#define G2 2              // batch groups of 16 per team (32 batches/team)

#define NJT1 4
#define NJT2 8
#define NJT3 16
#define NKB1 3
#define NKB2 6
#define NKB3 12

#define WSZ1 (NJT1*4*NKB1*512)   // 24576 halfs
#define WSZ2 (NJT2*4*NKB2*512)   // 98304
#define WSZ3 (NJT3*4*NKB3*512)   // 393216
#define WTOT (WSZ1+WSZ2+WSZ3)    // 516096 halfs

#define H2SLOT 4096              // [g][16][128] halfs
#define H2TEAM (8*H2SLOT)        // depth 8
#define H3SLOT 8192              // [h][g][16][128] halfs
#define H3TEAM (4*H3SLOT)        // depth 4
#define PRTEAM 512               // [slot4][h][g][16][2] floats
#define CAP_WAIT (1<<22)

typedef _Float16 half8 __attribute__((ext_vector_type(8)));
typedef _Float16 half4 __attribute__((ext_vector_type(4)));
typedef float f32x4 __attribute__((ext_vector_type(4)));

union H4u { unsigned long long u; half4 h; };

__device__ __forceinline__ float sigm(float x) {
  return __fdividef(1.f, 1.f + __expf(-x));
}
__device__ __forceinline__ float tanh_fast(float x) {
  float t = __expf(-2.f * fabsf(x));
  float r = __fdividef(1.f - t, 1.f + t);
  return copysignf(r, x);
}

// ---- proven system-scope prims (R5) ----
__device__ __forceinline__ unsigned long long ld64p(const _Float16* p) {
  return __hip_atomic_load((const unsigned long long*)p, __ATOMIC_RELAXED,
                           __HIP_MEMORY_SCOPE_SYSTEM);
}
__device__ __forceinline__ void st64p(_Float16* p, half4 v) {
  H4u r; r.h = v;
  __hip_atomic_store((unsigned long long*)p, r.u, __ATOMIC_RELAXED,
                     __HIP_MEMORY_SCOPE_SYSTEM);
}
__device__ __forceinline__ float ldfp(const float* p) {
  return __hip_atomic_load(p, __ATOMIC_RELAXED, __HIP_MEMORY_SCOPE_SYSTEM);
}
__device__ __forceinline__ void stfp(float* p, float v) {
  __hip_atomic_store(p, v, __ATOMIC_RELAXED, __HIP_MEMORY_SCOPE_SYSTEM);
}
__device__ __forceinline__ void stflag(int* p, int v) {
  __hip_atomic_store(p, v, __ATOMIC_RELEASE, __HIP_MEMORY_SCOPE_SYSTEM);
}
// lane0 polls pA>=tA, lane1 polls pB>=tB; capped; others pass
__device__ __forceinline__ void wait2(const int* pA, int tA, const int* pB, int tB,
                                      volatile int* dead) {
  if (*dead) return;
  const int lane = threadIdx.x & 63;
  const int* p = (lane == 1) ? pB : pA;
  const int tg = (lane == 0) ? tA : (lane == 1 ? tB : (int)0x80000000);
  int iter = 0;
  while (true) {
    const int v = (lane < 2)
        ? __hip_atomic_load(p, __ATOMIC_RELAXED, __HIP_MEMORY_SCOPE_SYSTEM)
        : 0x7fffffff;
    if (__all(v >= tg)) break;
    if (++iter > CAP_WAIT) { if (lane == 0) *dead = 1; break; }
    __builtin_amdgcn_s_sleep(1);
  }
  asm volatile("" ::: "memory");
}
__device__ __forceinline__ void vm0() {
  asm volatile("s_waitcnt vmcnt(0)" ::: "memory");
}

// ---- prep: fp32 weights -> f16 MFMA A-fragment layout (verified R2-R8) --------
__global__ void prep_weights(const float* __restrict__ Wih1, const float* __restrict__ Whh1,
                             const float* __restrict__ Wih2, const float* __restrict__ Whh2,
                             const float* __restrict__ Wih3, const float* __restrict__ Whh3,
                             _Float16* __restrict__ WT) {
  int idx = blockIdx.x * blockDim.x + threadIdx.x;
  if (idx >= WTOT) return;
  float v = 0.f;
  if (idx < WSZ1) {
    const int e = idx, blk = e >> 9, wb = e & 511;
    const int lane = wb >> 3, j = wb & 7;
    const int tl = blk / NKB1, kk = blk % NKB1;
    const int q = tl / NJT1, jt = tl % NJT1;
    const int r = q * 64 + jt * 16 + (lane & 15);
    const int k = kk * 32 + ((lane >> 4) << 3) + j;
    if (k < 64)       v = Whh1[r * 64 + k];
    else if (k < 66)  v = Wih1[r * 2 + (k - 64)];
  } else if (idx < WSZ1 + WSZ2) {
    const int e = idx - WSZ1, blk = e >> 9, wb = e & 511;
    const int lane = wb >> 3, j = wb & 7;
    const int tl = blk / NKB2, kk = blk % NKB2;
    const int q = tl / NJT2, jt = tl % NJT2;
    const int r = q * 128 + jt * 16 + (lane & 15);
    const int k = kk * 32 + ((lane >> 4) << 3) + j;
    if (k < 64)       v = Wih2[r * 64 + k];
    else              v = Whh2[r * 128 + (k - 64)];
  } else {
    const int e = idx - WSZ1 - WSZ2, blk = e >> 9, wb = e & 511;
    const int lane = wb >> 3, j = wb & 7;
    const int tl = blk / NKB3, kk = blk % NKB3;
    const int q = tl / NJT3, jt = tl % NJT3;
    const int r = q * 256 + jt * 16 + (lane & 15);
    const int k = kk * 32 + ((lane >> 4) << 3) + j;
    if (k < 128)      v = Wih3[r * 128 + k];
    else              v = Whh3[r * 256 + (k - 128)];
  }
  WT[idx] = (_Float16)v;
}

// ---- main pipelined kernel ----------------------------------------------------
__global__ __launch_bounds__(256, 1) void pipe_main(
    const float* __restrict__ input, const int* __restrict__ future_p,
    const float* __restrict__ bih1, const float* __restrict__ bhh1,
    const float* __restrict__ bih2, const float* __restrict__ bhh2,
    const float* __restrict__ bih3, const float* __restrict__ bhh3,
    const float* __restrict__ Wlin, const float* __restrict__ blin,
    const _Float16* __restrict__ WT,
    _Float16* __restrict__ h2r, _Float16* __restrict__ h3r,
    float* __restrict__ pr, int* __restrict__ flags,
    float* __restrict__ out) {
  const int tid = threadIdx.x;
  const int w = tid >> 6, lane = tid & 63;
  const int n = lane & 15, l4 = lane >> 4;

  const int team = blockIdx.x & 31;
  const int role = blockIdx.x >> 5;    // 0 front, 1/2 halves
  const int b0 = team * 32;

  const int fut = *future_p;
  const int nsteps = T_SEQ - 1 + fut;  // 271

  int* fbase = flags + team * 192;
  int* fA = fbase;         // half0 done-count
  int* fB = fbase + 64;    // half1
  int* fF = fbase + 128;   // front
  _Float16* h2b = h2r + (size_t)team * H2TEAM;
  _Float16* h3b = h3r + (size_t)team * H3TEAM;
  float* prb = pr + (size_t)team * PRTEAM;

  __shared__ volatile int sh_dead;
  if (tid == 0) sh_dead = 0;

  if (role == 0) {
    // =================== front: L1 + L2 + LIN combine ===================
    __shared__ __align__(16) _Float16 xh1s[G2][16][104];  // [h1|x|pad]
    __shared__ __align__(16) _Float16 xh2s[G2][16][200];  // [h1|h2|pad]
    __shared__ float bs1[256], bs2[512], wlinF[2][192], blin_s[2];

    for (int i = tid; i < G2*16*104; i += 256) (&xh1s[0][0][0])[i] = (_Float16)0.f;
    for (int i = tid; i < G2*16*200; i += 256) (&xh2s[0][0][0])[i] = (_Float16)0.f;
    if (tid < 256) bs1[tid] = bih1[tid] + bhh1[tid];
    bs2[tid] = bih2[tid] + bhh2[tid];
    bs2[tid + 256] = bih2[tid + 256] + bhh2[tid + 256];
    if (tid < 192) { wlinF[0][tid] = Wlin[tid]; wlinF[1][tid] = Wlin[448 + tid]; }
    if (tid < 2) blin_s[tid] = blin[tid];

    half8 a1[4][3];
#pragma unroll
    for (int q = 0; q < 4; ++q)
#pragma unroll
      for (int kk = 0; kk < 3; ++kk)
        a1[q][kk] = *(const half8*)(WT + ((q*NJT1 + w)*NKB1 + kk)*512 + lane*8);
    half8 a2[2][4][6];
#pragma unroll
    for (int u = 0; u < 2; ++u)
#pragma unroll
      for (int q = 0; q < 4; ++q)
#pragma unroll
        for (int kk = 0; kk < 6; ++kk)
          a2[u][q][kk] = *(const half8*)(WT + WSZ1 + ((q*NJT2 + (u*4+w))*NKB2 + kk)*512 + lane*8);
    float c1[G2][4] = {}, c2[2][G2][4] = {};
    __syncthreads();

    for (int it = 0; it <= nsteps; ++it) {
      const int tp = it - 1;
      if (it >= T_SEQ)        wait2(fA, it, fB, it, &sh_dead);
      else if ((it & 3) == 0) wait2(fA, it - 4, fB, it - 4, &sh_dead);

      // ---- LIN(tp) = front part (h1,h2) + partials from halves ----
      if (tp >= T_SEQ - 1) {
        const int g = w >> 1, ch = w & 1;   // 4 waves cover g x ch
        const int kq = l4;                  // 0..3, 48 k each
        float acc = 0.f;
#pragma unroll
        for (int i = 0; i < 12; ++i) {
          const int k = kq*48 + i*4;
          const half4 xv = *(const half4*)(&xh2s[g][n][k]);
          const float* wl = &wlinF[ch][k];
          acc = fmaf(wl[0], (float)xv[0], acc);
          acc = fmaf(wl[1], (float)xv[1], acc);
          acc = fmaf(wl[2], (float)xv[2], acc);
          acc = fmaf(wl[3], (float)xv[3], acc);
        }
        acc += __shfl_xor(acc, 16, 64);
        acc += __shfl_xor(acc, 32, 64);
        if (l4 == 0) {
          const float* pp = prb + (tp & 3)*128 + g*32 + n*2 + ch;
          const float o = acc + blin_s[ch] + ldfp(pp) + ldfp(pp + 64);
          out[((size_t)(b0 + g*16 + n)*fut + (tp - (T_SEQ - 1)))*2 + ch] = o;
          xh1s[g][n][64 + ch] = (_Float16)o;
        }
      }
      if (it < T_SEQ && tid < 64) {
        const int g = tid >> 5, nn = (tid >> 1) & 15, ch = tid & 1;
        xh1s[g][nn][64 + ch] =
            (_Float16)input[((size_t)(b0 + g*16 + nn)*T_SEQ + it)*2 + ch];
      }
      __syncthreads();
      if (it == nsteps) break;

      // ---- L1(it) ----
      half8 bf1[G2][3];
#pragma unroll
      for (int g = 0; g < G2; ++g)
#pragma unroll
        for (int kk = 0; kk < 3; ++kk)
          bf1[g][kk] = *(const half8*)(&xh1s[g][n][kk*32 + l4*8]);
      __syncthreads();
#pragma unroll
      for (int g = 0; g < G2; ++g) {
        f32x4 acc[4];
#pragma unroll
        for (int q = 0; q < 4; ++q) acc[q] = *(const f32x4*)(&bs1[q*64 + w*16 + l4*4]);
#pragma unroll
        for (int q = 0; q < 4; ++q)
#pragma unroll
          for (int kk = 0; kk < 3; ++kk)
            acc[q] = __builtin_amdgcn_mfma_f32_16x16x32_f16(a1[q][kk], bf1[g][kk], acc[q], 0, 0, 0);
        half4 hv;
#pragma unroll
        for (int e = 0; e < 4; ++e) {
          const float cn = sigm(acc[1][e]) * c1[g][e] + sigm(acc[0][e]) * tanh_fast(acc[2][e]);
          const float h = sigm(acc[3][e]) * tanh_fast(cn);
          c1[g][e] = cn;
          hv[e] = (_Float16)h;
        }
        *(half4*)(&xh1s[g][n][w*16 + l4*4]) = hv;
        *(half4*)(&xh2s[g][n][w*16 + l4*4]) = hv;
      }
      __syncthreads();

      // ---- L2(it) ----
      half8 bf2[G2][6];
#pragma unroll
      for (int g = 0; g < G2; ++g)
#pragma unroll
        for (int kk = 0; kk < 6; ++kk)
          bf2[g][kk] = *(const half8*)(&xh2s[g][n][kk*32 + l4*8]);
      __syncthreads();
      const int slot = it & 7;
#pragma unroll
      for (int u = 0; u < 2; ++u)
#pragma unroll
        for (int g = 0; g < G2; ++g) {
          f32x4 acc[4];
#pragma unroll
          for (int q = 0; q < 4; ++q)
            acc[q] = *(const f32x4*)(&bs2[q*128 + (u*4+w)*16 + l4*4]);
#pragma unroll
          for (int q = 0; q < 4; ++q)
#pragma unroll
            for (int kk = 0; kk < 6; ++kk)
              acc[q] = __builtin_amdgcn_mfma_f32_16x16x32_f16(a2[u][q][kk], bf2[g][kk], acc[q], 0, 0, 0);
          half4 hv;
#pragma unroll
          for (int e = 0; e < 4; ++e) {
            const float cn = sigm(acc[1][e]) * c2[u][g][e] + sigm(acc[0][e]) * tanh_fast(acc[2][e]);
            const float h = sigm(acc[3][e]) * tanh_fast(cn);
            c2[u][g][e] = cn;
            hv[e] = (_Float16)h;
          }
          const int row = (u*4 + w)*16 + l4*4;
          *(half4*)(&xh2s[g][n][64 + row]) = hv;
          st64p(h2b + (size_t)slot*H2SLOT + g*2048 + n*128 + row, hv);
        }
      vm0();
      __syncthreads();
      if (tid == 0) stflag(fF, it + 1);
    }
  } else {
    // =================== L3 half ===================
    const int h = role - 1, hs = 1 - h;
    __shared__ __align__(16) _Float16 stage[G2][16][264];   // [h2(128)|sib(128)|pad]
    __shared__ __align__(16) _Float16 xh3own[G2][16][132];  // own 128 cols
    __shared__ float bs3s[4][2][4][16];                     // [w][u][q][col]
    __shared__ float wlp[2][128];

    for (int i = tid; i < G2*16*264; i += 256) (&stage[0][0][0])[i] = (_Float16)0.f;
    for (int i = tid; i < G2*16*132; i += 256) (&xh3own[0][0][0])[i] = (_Float16)0.f;
    {
      int i = tid;          // 256 threads x 2 rounds -> 512 bias entries
#pragma unroll
      for (int rnd = 0; rnd < 2; ++rnd, i += 256) {
        const int w2 = i >> 7, u = (i >> 6) & 1, q = (i >> 4) & 3, col = i & 15;
        const int r = q*256 + (h*8 + w2*2 + u)*16 + col;
        bs3s[w2][u][q][col] = bih3[r] + bhh3[r];
      }
    }
    if (tid < 256) {
      const int ch = tid >> 7, k = tid & 127;
      wlp[ch][k] = Wlin[ch*448 + 192 + h*128 + k];
    }
    half8 a3[2][4][12];
#pragma unroll
    for (int u = 0; u < 2; ++u)
#pragma unroll
      for (int q = 0; q < 4; ++q)
#pragma unroll
        for (int kk = 0; kk < 12; ++kk)
          a3[u][q][kk] = *(const half8*)(WT + WSZ1 + WSZ2 +
              ((q*NJT3 + (h*8 + w*2 + u))*NKB3 + kk)*512 + lane*8);
    float c3[G2][2][4] = {};
    int* fme  = h ? fB : fA;
    int* fsib = h ? fA : fB;
    __syncthreads();

    for (int t = 0; t < nsteps; ++t) {
      wait2(fsib, t, fF, t + 1, &sh_dead);
      const int s2 = t & 7, s3 = (t - 1) & 3;
#pragma unroll
      for (int g = 0; g < G2; ++g) {
        // phase 1: own-half fragments from LDS + wave-split remote -> stage
        half8 bfo[4];
#pragma unroll
        for (int s = 0; s < 4; ++s)
          bfo[s] = *(const half8*)(&xh3own[g][n][s*32 + l4*8]);
#pragma unroll
        for (int j = 0; j < 2; ++j) {
          const int kst = 2*w + j;
          H4u v0, v1;
          if (kst < 4) {
            const _Float16* p = h2b + (size_t)s2*H2SLOT + g*2048 + n*128 + kst*32 + l4*8;
            v0.u = ld64p(p); v1.u = ld64p(p + 4);
          } else if (t > 0) {
            const _Float16* p = h3b + (size_t)s3*H3SLOT + hs*4096 + g*2048 + n*128
                              + (kst - 4)*32 + l4*8;
            v0.u = ld64p(p); v1.u = ld64p(p + 4);
          } else { v0.u = 0; v1.u = 0; }
          *(half4*)(&stage[g][n][kst*32 + l4*8]) = v0.h;
          *(half4*)(&stage[g][n][kst*32 + l4*8 + 4]) = v1.h;
        }
        __syncthreads();
        // phase 2: assemble bf, MFMA, pointwise, write own hv
        half8 bf[12];
#pragma unroll
        for (int s = 0; s < 4; ++s) {
          bf[s] = *(const half8*)(&stage[g][n][s*32 + l4*8]);               // h2
          bf[4 + 4*h + s] = bfo[s];                                        // own h3
          bf[4 + 4*hs + s] = *(const half8*)(&stage[g][n][128 + s*32 + l4*8]); // sib h3
        }
        f32x4 acc[2][4];
#pragma unroll
        for (int u = 0; u < 2; ++u)
#pragma unroll
          for (int q = 0; q < 4; ++q)
            acc[u][q] = *(const f32x4*)(&bs3s[w][u][q][l4*4]);
#pragma unroll
        for (int u = 0; u < 2; ++u)
#pragma unroll
          for (int q = 0; q < 4; ++q)
#pragma unroll
            for (int kk = 0; kk < 12; ++kk)
              acc[u][q] = __builtin_amdgcn_mfma_f32_16x16x32_f16(a3[u][q][kk], bf[kk], acc[u][q], 0, 0, 0);
#pragma unroll
        for (int u = 0; u < 2; ++u) {
          half4 hv;
#pragma unroll
          for (int e = 0; e < 4; ++e) {
            const float cn = sigm(acc[u][1][e]) * c3[g][u][e]
                           + sigm(acc[u][0][e]) * tanh_fast(acc[u][2][e]);
            const float hh = sigm(acc[u][3][e]) * tanh_fast(cn);
            c3[g][u][e] = cn;
            hv[e] = (_Float16)hh;
          }
          const int c = (w*2 + u)*16 + l4*4;
          *(half4*)(&xh3own[g][n][c]) = hv;
          st64p(h3b + (size_t)(t & 3)*H3SLOT + h*4096 + g*2048 + n*128 + c, hv);
        }
        __syncthreads();
      }
      vm0();
      __syncthreads();
      // LIN partial over own 128 cols (future steps only)
      if (t >= T_SEQ - 1) {
        const int g = w >> 1, ch = w & 1;
        float pa = 0.f;
#pragma unroll
        for (int i = 0; i < 8; ++i) {
          const int k = l4*32 + i*4;
          const half4 xv = *(const half4*)(&xh3own[g][n][k]);
          const float* wl = &wlp[ch][k];
          pa = fmaf(wl[0], (float)xv[0], pa);
          pa = fmaf(wl[1], (float)xv[1], pa);
          pa = fmaf(wl[2], (float)xv[2], pa);
          pa = fmaf(wl[3], (float)xv[3], pa);
        }
        pa += __shfl_xor(pa, 16, 64);
        pa += __shfl_xor(pa, 32, 64);
        if (l4 == 0)
          stfp(prb + (t & 3)*128 + h*64 + g*32 + n*2 + ch, pa);
        vm0();
        __syncthreads();
      }
      if (tid == 0) stflag(fme, t + 1);
    }
  }
}

extern "C" void kernel_launch(void* const* d_in, const int* in_sizes, int n_in,
                              void* d_out, int out_size, void* d_ws, size_t ws_size,
                              hipStream_t stream) {
  const float* input = (const float*)d_in[0];
  const int*   fut   = (const int*)d_in[1];
  const float* Wih1  = (const float*)d_in[2];
  const float* Whh1  = (const float*)d_in[3];
  const float* bih1  = (const float*)d_in[4];
  const float* bhh1  = (const float*)d_in[5];
  const float* Wih2  = (const float*)d_in[6];
  const float* Whh2  = (const float*)d_in[7];
  const float* bih2  = (const float*)d_in[8];
  const float* bhh2  = (const float*)d_in[9];
  const float* Wih3  = (const float*)d_in[10];
  const float* Whh3  = (const float*)d_in[11];
  const float* bih3  = (const float*)d_in[12];
  const float* bhh3  = (const float*)d_in[13];
  const float* Wlin  = (const float*)d_in[14];
  const float* blin  = (const float*)d_in[15];
  float* out = (float*)d_out;

  _Float16* WT  = (_Float16*)d_ws;
  _Float16* h2r = WT + WTOT;
  _Float16* h3r = h2r + (size_t)NTEAM * H2TEAM;
  float*    pr  = (float*)(h3r + (size_t)NTEAM * H3TEAM);
  int*    flags = (int*)(pr + (size_t)NTEAM * PRTEAM);
  const size_t flag_bytes = (size_t)NTEAM * 192 * sizeof(int);

  prep_weights<<<(WTOT + 255) / 256, 256, 0, stream>>>(Wih1, Whh1, Wih2, Whh2, Wih3, Whh3, WT);
  hipMemsetAsync(flags, 0, flag_bytes, stream);
  pipe_main<<<96, 256, 0, stream>>>(input, fut,
                                    bih1, bhh1, bih2, bhh2, bih3, bhh3,
                                    Wlin, blin, WT, h2r, h3r, pr, flags, out);
}